// Round 1
// baseline (2225.839 us; speedup 1.0000x reference)
//
#include <hip/hip_runtime.h>

// Problem constants (match reference setup_inputs()).
#define N_EDGES  1000000
#define N_NODES  100000
#define DIM      128
// Each thread handles one float4 => 32 threads per edge.
#define THREADS_PER_EDGE 32

__global__ void __launch_bounds__(256)
tp_scatter_kernel(const float* __restrict__ x,
                  const float* __restrict__ y,
                  const float* __restrict__ coeffs,
                  const int*   __restrict__ src,
                  const int*   __restrict__ dst,
                  float*       __restrict__ out)
{
    int gid = blockIdx.x * 256 + threadIdx.x;
    int e = gid >> 5;          // edge index
    int q = gid & 31;          // float4 slot within the 128-wide row
    if (e >= N_EDGES) return;

    int s = src[e];
    int d = dst[e];
    // segment index for element range [q*4, q*4+3] is (q*4)/32 = q>>3
    float c = coeffs[q >> 3];

    const float4 yv = *reinterpret_cast<const float4*>(y + (size_t)e * DIM + q * 4);
    const float4 xv = *reinterpret_cast<const float4*>(x + (size_t)s * DIM + q * 4);

    float* op = out + (size_t)d * DIM + q * 4;
    atomicAdd(op + 0, xv.x * yv.x * c);
    atomicAdd(op + 1, xv.y * yv.y * c);
    atomicAdd(op + 2, xv.z * yv.z * c);
    atomicAdd(op + 3, xv.w * yv.w * c);
}

extern "C" void kernel_launch(void* const* d_in, const int* in_sizes, int n_in,
                              void* d_out, int out_size, void* d_ws, size_t ws_size,
                              hipStream_t stream)
{
    const float* x      = (const float*)d_in[0];
    const float* y      = (const float*)d_in[1];
    const float* coeffs = (const float*)d_in[2];
    const int*   src    = (const int*)d_in[3];
    const int*   dst    = (const int*)d_in[4];
    float* out = (float*)d_out;

    // Harness re-poisons d_out to 0xAA before every timed launch — zero it.
    hipMemsetAsync(d_out, 0, (size_t)out_size * sizeof(float), stream);

    const long long total_threads = (long long)N_EDGES * THREADS_PER_EDGE;
    const int block = 256;
    const int grid = (int)((total_threads + block - 1) / block);
    tp_scatter_kernel<<<grid, block, 0, stream>>>(x, y, coeffs, src, dst, out);
}

// Round 2
// 847.955 us; speedup vs baseline: 2.6249x; 2.6249x over previous
//
#include <hip/hip_runtime.h>

#define N_EDGES  1000000
#define N_NODES  100000
#define DIM      128

// Workspace layout (uint32 element offsets into d_ws)
#define WS_COUNTS   0            // [100000]  histogram (zeroed)
#define WS_COUNTS2  100000       // [100000]  scatter cursors (zeroed)
#define WS_OFFSETS  200000       // [100000]  exclusive prefix sums
#define WS_BLKSUMS  300000       // [128]
#define WS_BLKOFFS  300128       // [128]
#define WS_SORTED   300256       // [1000000] edge ids sorted by dst

#define SCAN_CHUNK  1024
#define NBLK        ((N_NODES + SCAN_CHUNK - 1) / SCAN_CHUNK)   // 98

__global__ void __launch_bounds__(256)
hist_kernel(const int* __restrict__ dst, unsigned* __restrict__ counts)
{
    int e = blockIdx.x * 256 + threadIdx.x;
    if (e < N_EDGES) atomicAdd(&counts[dst[e]], 1u);
}

__global__ void __launch_bounds__(256)
reduce_blocks(const unsigned* __restrict__ counts, unsigned* __restrict__ blkSums)
{
    __shared__ unsigned lds[256];
    int b = blockIdx.x, t = threadIdx.x;
    int base = b * SCAN_CHUNK + t * 4;
    unsigned s = 0;
    #pragma unroll
    for (int k = 0; k < 4; k++) { int i = base + k; if (i < N_NODES) s += counts[i]; }
    lds[t] = s; __syncthreads();
    for (int off = 128; off > 0; off >>= 1) {
        if (t < off) lds[t] += lds[t + off];
        __syncthreads();
    }
    if (t == 0) blkSums[b] = lds[0];
}

__global__ void scan_sums(const unsigned* __restrict__ blkSums, unsigned* __restrict__ blkOffs)
{
    if (threadIdx.x == 0) {
        unsigned r = 0;
        for (int i = 0; i < NBLK; i++) { blkOffs[i] = r; r += blkSums[i]; }
    }
}

__global__ void __launch_bounds__(256)
scan_blocks(const unsigned* __restrict__ counts, const unsigned* __restrict__ blkOffs,
            unsigned* __restrict__ offsets)
{
    __shared__ unsigned lds[256];
    int b = blockIdx.x, t = threadIdx.x;
    int base = b * SCAN_CHUNK + t * 4;
    unsigned v[4]; unsigned s = 0;
    #pragma unroll
    for (int k = 0; k < 4; k++) { int i = base + k; v[k] = (i < N_NODES) ? counts[i] : 0u; s += v[k]; }
    lds[t] = s; __syncthreads();
    // Hillis-Steele inclusive scan over 256 per-thread sums
    for (int off = 1; off < 256; off <<= 1) {
        unsigned add = (t >= off) ? lds[t - off] : 0u;
        __syncthreads();
        lds[t] += add;
        __syncthreads();
    }
    unsigned excl = (t == 0) ? 0u : lds[t - 1];
    unsigned run = blkOffs[b] + excl;
    #pragma unroll
    for (int k = 0; k < 4; k++) { int i = base + k; if (i < N_NODES) offsets[i] = run; run += v[k]; }
}

__global__ void __launch_bounds__(256)
scatter_kernel(const int* __restrict__ dst, const unsigned* __restrict__ offsets,
               unsigned* __restrict__ cursors, unsigned* __restrict__ sorted)
{
    int e = blockIdx.x * 256 + threadIdx.x;
    if (e >= N_EDGES) return;
    int d = dst[e];
    unsigned pos = offsets[d] + atomicAdd(&cursors[d], 1u);
    sorted[pos] = (unsigned)e;
}

// One wave (64 lanes) per node; lane l owns columns [2l, 2l+1].
__global__ void __launch_bounds__(256)
gather_reduce(const float* __restrict__ x, const float* __restrict__ y,
              const float* __restrict__ coeffs, const int* __restrict__ src,
              const unsigned* __restrict__ offsets, const unsigned* __restrict__ counts,
              const unsigned* __restrict__ sorted, float* __restrict__ out)
{
    int wave = threadIdx.x >> 6;
    int lane = threadIdx.x & 63;
    int n = blockIdx.x * 4 + wave;
    if (n >= N_NODES) return;

    const int col = lane * 2;
    float c = coeffs[lane >> 4];          // segment = (2l)/32 = l>>4
    unsigned start = offsets[n];
    unsigned cnt   = counts[n];
    unsigned j = start, end = start + cnt;

    float ax = 0.f, ay = 0.f;
    for (; j + 2 <= end; j += 2) {
        unsigned e0 = sorted[j], e1 = sorted[j + 1];
        int s0 = src[e0], s1 = src[e1];
        float2 y0 = *reinterpret_cast<const float2*>(y + (size_t)e0 * DIM + col);
        float2 x0 = *reinterpret_cast<const float2*>(x + (size_t)s0 * DIM + col);
        float2 y1 = *reinterpret_cast<const float2*>(y + (size_t)e1 * DIM + col);
        float2 x1 = *reinterpret_cast<const float2*>(x + (size_t)s1 * DIM + col);
        ax += x0.x * y0.x; ay += x0.y * y0.y;
        ax += x1.x * y1.x; ay += x1.y * y1.y;
    }
    if (j < end) {
        unsigned e0 = sorted[j];
        int s0 = src[e0];
        float2 y0 = *reinterpret_cast<const float2*>(y + (size_t)e0 * DIM + col);
        float2 x0 = *reinterpret_cast<const float2*>(x + (size_t)s0 * DIM + col);
        ax += x0.x * y0.x; ay += x0.y * y0.y;
    }
    float2 r; r.x = c * ax; r.y = c * ay;
    *reinterpret_cast<float2*>(out + (size_t)n * DIM + col) = r;
}

extern "C" void kernel_launch(void* const* d_in, const int* in_sizes, int n_in,
                              void* d_out, int out_size, void* d_ws, size_t ws_size,
                              hipStream_t stream)
{
    const float* x      = (const float*)d_in[0];
    const float* y      = (const float*)d_in[1];
    const float* coeffs = (const float*)d_in[2];
    const int*   src    = (const int*)d_in[3];
    const int*   dst    = (const int*)d_in[4];
    float* out = (float*)d_out;

    unsigned* ws = (unsigned*)d_ws;
    unsigned* counts  = ws + WS_COUNTS;
    unsigned* cursors = ws + WS_COUNTS2;
    unsigned* offsets = ws + WS_OFFSETS;
    unsigned* blkSums = ws + WS_BLKSUMS;
    unsigned* blkOffs = ws + WS_BLKOFFS;
    unsigned* sorted  = ws + WS_SORTED;

    // Zero histogram + cursors (contiguous region). ws is poisoned 0xAA each call.
    hipMemsetAsync(d_ws, 0, 200000 * sizeof(unsigned), stream);

    hist_kernel<<<(N_EDGES + 255) / 256, 256, 0, stream>>>(dst, counts);
    reduce_blocks<<<NBLK, 256, 0, stream>>>(counts, blkSums);
    scan_sums<<<1, 64, 0, stream>>>(blkSums, blkOffs);
    scan_blocks<<<NBLK, 256, 0, stream>>>(counts, blkOffs, offsets);
    scatter_kernel<<<(N_EDGES + 255) / 256, 256, 0, stream>>>(dst, offsets, cursors, sorted);
    gather_reduce<<<(N_NODES + 3) / 4, 256, 0, stream>>>(x, y, coeffs, src, offsets, counts, sorted, out);
}